// Round 5
// baseline (396.742 us; speedup 1.0000x reference)
//
#include <hip/hip_runtime.h>
#include <math.h>

#define Bn 4
#define Nn 2048
#define Hn 8
#define HDn 32
#define Dn 256
#define MQ 512  // m-split: 4 partials merged in oproj

typedef _Float16 h1;
typedef __attribute__((ext_vector_type(8))) _Float16 h8;
typedef __attribute__((ext_vector_type(4))) float fx4;

#define QSCALE 0.35355339059327373f  // 2/sqrt(HD): applied at exp time
// |S_raw| <= HD = 32, |S_raw*QSCALE*topo| <= 11.32 -> fixed softmax shift safe:
// p = e^{S-4} in [2.2e-7, 1503] -- fits f16, no running max needed.
#define SOFTMAX_SHIFT 4.0f

// ---------------------------------------------------------------------------
// Kernel 0: W -> f16 transpose via LDS tiles (coalesced both sides)
//   WT[w][out][d], 64x64 tiles
// ---------------------------------------------------------------------------
__global__ __launch_bounds__(256) void cvtW_kernel(
    const float* __restrict__ Wq, const float* __restrict__ Wk,
    const float* __restrict__ Wv, h1* __restrict__ WT)
{
    __shared__ float tw[64][65];
    const int w = blockIdx.z;
    const int d0 = blockIdx.y * 64, o0 = blockIdx.x * 64;
    const float* W = (w == 0) ? Wq : (w == 1) ? Wk : Wv;
    const int rr = threadIdx.x >> 6, cc = threadIdx.x & 63;
#pragma unroll
    for (int i = 0; i < 16; ++i)
        tw[rr + i * 4][cc] = W[(size_t)(d0 + rr + i * 4) * 256 + o0 + cc];
    __syncthreads();
#pragma unroll
    for (int i = 0; i < 16; ++i) {
        const int row = rr + i * 4;
        WT[(size_t)w * 65536 + (size_t)(o0 + row) * 256 + d0 + cc] = (h1)tw[cc][row];
    }
}

// ---------------------------------------------------------------------------
// Kernel 1: QKV projection via f16 MFMA (x split hi/lo for ~f32 accuracy)
// Block = 4 waves x 16 rows = 64 rows x 256 cols of ONE W (grid.y selects).
// Epilogue: q/k features staged in LDS -> coalesced h8 stores (wave-local);
// v -> LDS transpose -> vT.
// Fragment layouts (verified gfx950):
//   A: A[m=lane&15][k=quad*8+j], B: B[k=quad*8+j][n=lane&15],
//   C/D: row=quad*4+reg, col=lane&15
// ---------------------------------------------------------------------------
#define FPAD 528  // feature row stride: conflict-free writes, 16B-aligned rows
__global__ __launch_bounds__(256, 2) void proj_kernel(
    const float* __restrict__ x, const h1* __restrict__ WT,
    const float* __restrict__ bq, const float* __restrict__ bk,
    const float* __restrict__ bv,
    h1* __restrict__ fq, h1* __restrict__ fk, h1* __restrict__ vT)
{
    __shared__ __align__(16) h1 smem[4 * 16 * FPAD];  // 67.6 KB; vst aliases it
    const int tid = threadIdx.x;
    const int w = tid >> 6;
    const int lane = tid & 63;
    const int quad = lane >> 4;
    const int l15 = lane & 15;
    const int wsel = blockIdx.y;
    const int r0 = blockIdx.x * 64;
    const int arow = r0 + w * 16 + l15;
    const int b = r0 >> 11, n0 = r0 & (Nn - 1);

    // x -> hi/lo f16 A-fragments (on-the-fly conversion)
    h8 Ahi[8], Alo[8];
#pragma unroll
    for (int ks = 0; ks < 8; ++ks) {
        float xv[8];
        *(float4*)&xv[0] = *(const float4*)&x[(size_t)arow * 256 + ks * 32 + quad * 8];
        *(float4*)&xv[4] = *(const float4*)&x[(size_t)arow * 256 + ks * 32 + quad * 8 + 4];
#pragma unroll
        for (int j = 0; j < 8; ++j) {
            const h1 hi = (h1)xv[j];
            Ahi[ks][j] = hi;
            Alo[ks][j] = (h1)(xv[j] - (float)hi);
        }
    }

    const h1* WTw = WT + (size_t)wsel * 65536;
    fx4 acc[16];
#pragma unroll
    for (int ct = 0; ct < 16; ++ct) acc[ct] = (fx4){0.f, 0.f, 0.f, 0.f};

#pragma unroll
    for (int ks = 0; ks < 8; ++ks) {
        h8 Bf[16];
#pragma unroll
        for (int ct = 0; ct < 16; ++ct)
            Bf[ct] = *(const h8*)&WTw[(size_t)(ct * 16 + l15) * 256 + ks * 32 + quad * 8];
#pragma unroll
        for (int ct = 0; ct < 16; ++ct) {
            acc[ct] = __builtin_amdgcn_mfma_f32_16x16x32_f16(Ahi[ks], Bf[ct], acc[ct], 0, 0, 0);
            acc[ct] = __builtin_amdgcn_mfma_f32_16x16x32_f16(Alo[ks], Bf[ct], acc[ct], 0, 0, 0);
        }
    }

    if (wsel < 2) {
        const float* bias = (wsel == 0) ? bq : bk;
        h1* f = (wsel == 0) ? fq : fk;
        h1* fst = smem + w * 16 * FPAD;  // wave-local: no barrier needed
#pragma unroll
        for (int ct = 0; ct < 16; ++ct) {
            const int c = ct * 16 + l15;
            const float bb = bias[c];
            const int hh = c >> 5, dd = c & 31;
#pragma unroll
            for (int r = 0; r < 4; ++r) {
                float sv, cv;
                __sincosf(acc[ct][r] + bb, &sv, &cv);
                h1* fp = fst + (quad * 4 + r) * FPAD + hh * 64 + dd;
                fp[0]  = (h1)cv;
                fp[32] = (h1)sv;
            }
        }
        // wave-local coalesced store: lane -> (head = l>>3, chunk = l&7)
        const int hh = lane >> 3, ch = lane & 7;
#pragma unroll
        for (int rr = 0; rr < 16; ++rr) {
            const h8 val = *(const h8*)&fst[rr * FPAD + hh * 64 + ch * 8];
            const int n = n0 + w * 16 + rr;
            *(h8*)&f[((size_t)(b * Hn + hh) * Nn + n) * 64 + ch * 8] = val;
        }
    } else {
        // v: stage to LDS, cooperative transposed write (coalesced vT rows)
        h1 (*vst)[264] = (h1(*)[264])smem;
#pragma unroll
        for (int ct = 0; ct < 16; ++ct) {
            const int c = ct * 16 + l15;
            const float bb = bv[c];
#pragma unroll
            for (int r = 0; r < 4; ++r)
                vst[w * 16 + quad * 4 + r][c] = (h1)(acc[ct][r] + bb);
        }
        __syncthreads();
        const int c = tid;
        const int hh = c >> 5, dd = c & 31;
        h1* vp = vT + ((size_t)((b * Hn + hh) * HDn + dd)) * Nn + n0;
#pragma unroll
        for (int g = 0; g < 8; ++g) {
            h8 pk;
#pragma unroll
            for (int j = 0; j < 8; ++j) pk[j] = vst[g * 8 + j][c];
            *(h8*)(vp + g * 8) = pk;
        }
    }
}

// ---------------------------------------------------------------------------
// Kernel 2: fused attention, barrier-free, unroll-2 double-buffered pipeline.
// Wave = (b, h, 32 q-rows, m-quarter). Block = 4 waves = 4 heads (same topo ->
// L1/L2 hits). Grid 2048 blocks. NO register rotation: two buffer sets
// alternate, so the compiler can emit vmcnt(N>0) before each compute phase
// and prefetch (distance = 2 tiles) stays in flight across a full phase.
// Fixed-shift softmax: no reductions in the loop.
// ---------------------------------------------------------------------------
__global__ __launch_bounds__(256, 4) void attn_kernel(
    const h1* __restrict__ fq, const h1* __restrict__ fk, const h1* __restrict__ vT,
    const float* __restrict__ topo, float* __restrict__ pacc, float* __restrict__ pl)
{
    __shared__ __align__(16) h1 Pw[4][32][40];  // per-wave P transpose buffer

    const int b = blockIdx.y;
    const int n0 = blockIdx.x * 32;
    const int z = blockIdx.z;          // z = hg + 2*mq
    const int mq = z >> 1;
    const int tid = threadIdx.x;
    const int w = tid >> 6;
    const int h = (z & 1) * 4 + w;
    const int lane = tid & 63;
    const int quad = lane >> 4;
    const int l15 = lane & 15;

    const h1* qfh = fq + (size_t)(b * Hn + h) * Nn * 64;
    const h1* kfh = fk + (size_t)(b * Hn + h) * Nn * 64;
    const h1* vTh = vT + (size_t)(b * Hn + h) * HDn * Nn;
    const float* tpb = topo + (size_t)b * Nn * Nn + (size_t)n0 * Nn;

    h8 qfr[2][2];
#pragma unroll
    for (int qs = 0; qs < 2; ++qs)
#pragma unroll
        for (int ks = 0; ks < 2; ++ks)
            qfr[qs][ks] = *(const h8*)(qfh + (size_t)(n0 + qs * 16 + l15) * 64 + ks * 32 + quad * 8);

    fx4 acc[2][2];
    float lsum[2][4];
#pragma unroll
    for (int qs = 0; qs < 2; ++qs) {
#pragma unroll
        for (int ds = 0; ds < 2; ++ds) acc[qs][ds] = (fx4){0.f, 0.f, 0.f, 0.f};
#pragma unroll
        for (int r = 0; r < 4; ++r) lsum[qs][r] = 0.f;
    }

    const int mbase = mq * MQ;
    const fx4 z4 = {0.f, 0.f, 0.f, 0.f};
    const int NIT = MQ / 32;  // 16

#define LOAD_TILE(KF, BV, TP, M0)                                              \
    do {                                                                       \
        _Pragma("unroll") for (int ms = 0; ms < 2; ++ms)                       \
            _Pragma("unroll") for (int ks = 0; ks < 2; ++ks)                   \
                KF[ms][ks] = *(const h8*)(kfh +                                \
                    (size_t)((M0) + ms * 16 + l15) * 64 + ks * 32 + quad * 8); \
        _Pragma("unroll") for (int ds = 0; ds < 2; ++ds)                       \
            BV[ds] = *(const h8*)(vTh +                                        \
                (size_t)(ds * 16 + l15) * Nn + (M0) + quad * 8);               \
        _Pragma("unroll") for (int qs = 0; qs < 2; ++qs)                       \
            _Pragma("unroll") for (int r = 0; r < 4; ++r) {                    \
                const float* tr = tpb +                                        \
                    (size_t)(qs * 16 + quad * 4 + r) * Nn + (M0) + l15;        \
                TP[qs][r][0] = tr[0];                                          \
                TP[qs][r][1] = tr[16];                                         \
            }                                                                  \
    } while (0)

#define COMPUTE_TILE(KF, BV, TP)                                               \
    do {                                                                       \
        fx4 S[2][2];                                                           \
        _Pragma("unroll") for (int qs = 0; qs < 2; ++qs)                       \
            _Pragma("unroll") for (int ms = 0; ms < 2; ++ms) {                 \
                fx4 tmp = __builtin_amdgcn_mfma_f32_16x16x32_f16(              \
                    qfr[qs][0], KF[ms][0], z4, 0, 0, 0);                       \
                S[qs][ms] = __builtin_amdgcn_mfma_f32_16x16x32_f16(            \
                    qfr[qs][1], KF[ms][1], tmp, 0, 0, 0);                      \
            }                                                                  \
        _Pragma("unroll") for (int qs = 0; qs < 2; ++qs)                       \
            _Pragma("unroll") for (int ms = 0; ms < 2; ++ms)                   \
                _Pragma("unroll") for (int r = 0; r < 4; ++r) {                \
                    const float ts = S[qs][ms][r] * TP[qs][r][ms];             \
                    const float p = __expf(fmaf(ts, QSCALE, -SOFTMAX_SHIFT));  \
                    lsum[qs][r] += p;                                          \
                    Pw[w][qs * 16 + quad * 4 + r][ms * 16 + l15] = (h1)p;      \
                }                                                              \
        h8 aP[2];                                                              \
        _Pragma("unroll") for (int qs = 0; qs < 2; ++qs)                       \
            aP[qs] = *(const h8*)&Pw[w][qs * 16 + l15][quad * 8];              \
        _Pragma("unroll") for (int qs = 0; qs < 2; ++qs)                       \
            _Pragma("unroll") for (int ds = 0; ds < 2; ++ds)                   \
                acc[qs][ds] = __builtin_amdgcn_mfma_f32_16x16x32_f16(          \
                    aP[qs], BV[ds], acc[qs][ds], 0, 0, 0);                     \
    } while (0)

    h8 kf0[2][2], kf1[2][2], bV0[2], bV1[2];
    float tp0[2][4][2], tp1[2][4][2];
    LOAD_TILE(kf0, bV0, tp0, mbase);
    LOAD_TILE(kf1, bV1, tp1, mbase + 32);

    for (int it = 0; it < NIT / 2; ++it) {
        const int mA = mbase + ((2 * it + 2 < NIT) ? (2 * it + 2) : (NIT - 1)) * 32;
        const int mB = mbase + ((2 * it + 3 < NIT) ? (2 * it + 3) : (NIT - 1)) * 32;
        COMPUTE_TILE(kf0, bV0, tp0);
        LOAD_TILE(kf0, bV0, tp0, mA);   // prefetch tile 2it+2 (clamped)
        COMPUTE_TILE(kf1, bV1, tp1);
        LOAD_TILE(kf1, bV1, tp1, mB);   // prefetch tile 2it+3 (clamped)
    }
#undef LOAD_TILE
#undef COMPUTE_TILE

    // epilogue: reduce l across the 16 col-lanes, write partials
#pragma unroll
    for (int qs = 0; qs < 2; ++qs)
#pragma unroll
        for (int r = 0; r < 4; ++r)
#pragma unroll
            for (int off = 1; off <= 8; off <<= 1)
                lsum[qs][r] += __shfl_xor(lsum[qs][r], off);

    float* paccm = pacc + (size_t)mq * Bn * Nn * Dn;
    float* plm   = pl   + (size_t)mq * Bn * Nn * Hn;
#pragma unroll
    for (int qs = 0; qs < 2; ++qs)
#pragma unroll
        for (int r = 0; r < 4; ++r) {
            const size_t grow = (size_t)b * Nn + n0 + qs * 16 + quad * 4 + r;
            paccm[grow * Dn + h * HDn + l15]      = acc[qs][0][r];
            paccm[grow * Dn + h * HDn + 16 + l15] = acc[qs][1][r];
            if (l15 == 0) plm[grow * Hn + h] = lsum[qs][r];
        }
}

// ---------------------------------------------------------------------------
// Kernel 3: merge 4 partials + output projection. 8 rows/block, thread=col.
// ---------------------------------------------------------------------------
__global__ __launch_bounds__(256) void oproj_kernel(
    const float* __restrict__ pacc, const float* __restrict__ pl,
    const float* __restrict__ Wo, const float* __restrict__ bo,
    float* __restrict__ out)
{
    __shared__ float ysT[256][12];  // [col][row], float4-aligned rows
    const int t = threadIdx.x;
    const int r0 = blockIdx.x * 8;
    const int h = t >> 5;
    const size_t PACC = (size_t)Bn * Nn * Dn;
    const size_t PL = (size_t)Bn * Nn * Hn;
#pragma unroll
    for (int i = 0; i < 8; ++i) {
        const size_t row = (size_t)(r0 + i);
        float l = 0.f, yv = 0.f;
#pragma unroll
        for (int m = 0; m < 4; ++m) {
            l  += pl[m * PL + row * Hn + h];
            yv += pacc[m * PACC + row * Dn + t];
        }
        ysT[t][i] = yv * __builtin_amdgcn_rcpf(l);
    }
    __syncthreads();

    float acc8[8];
#pragma unroll
    for (int i = 0; i < 8; ++i) acc8[i] = 0.f;
#pragma unroll 4
    for (int d = 0; d < 256; ++d) {
        const float wv = Wo[d * 256 + t];
        float yy[8];
        *(float4*)&yy[0] = *(const float4*)&ysT[d][0];  // broadcast reads
        *(float4*)&yy[4] = *(const float4*)&ysT[d][4];
#pragma unroll
        for (int i = 0; i < 8; ++i) acc8[i] = fmaf(yy[i], wv, acc8[i]);
    }
    const float bb = bo[t];
#pragma unroll
    for (int i = 0; i < 8; ++i)
        out[(size_t)(r0 + i) * 256 + t] = acc8[i] + bb;
}

// ---------------------------------------------------------------------------
extern "C" void kernel_launch(void* const* d_in, const int* in_sizes, int n_in,
                              void* d_out, int out_size, void* d_ws, size_t ws_size,
                              hipStream_t stream)
{
    const float* x    = (const float*)d_in[0];
    const float* topo = (const float*)d_in[1];
    const float* Wq   = (const float*)d_in[2];
    const float* bq   = (const float*)d_in[3];
    const float* Wk   = (const float*)d_in[4];
    const float* bk   = (const float*)d_in[5];
    const float* Wv   = (const float*)d_in[6];
    const float* bv   = (const float*)d_in[7];
    const float* Wo   = (const float*)d_in[8];
    const float* bo   = (const float*)d_in[9];
    float* out = (float*)d_out;

    char* ws = (char*)d_ws;
    const size_t MB = 1024 * 1024;
    // ws: WT 384KB @0 | fq 8MB @1 | fk 8MB @9 | vT 4MB @17 | pacc 32MB @21 | pl 1MB @53
    h1* WT = (h1*)ws;
    h1* fq = (h1*)(ws + 1 * MB);
    h1* fk = (h1*)(ws + 9 * MB);
    h1* vT = (h1*)(ws + 17 * MB);
    float* pacc = (float*)(ws + 21 * MB);
    float* pl   = (float*)(ws + 53 * MB);

    cvtW_kernel<<<dim3(4, 4, 3), 256, 0, stream>>>(Wq, Wk, Wv, WT);
    proj_kernel<<<dim3(128, 3), 256, 0, stream>>>(x, WT, bq, bk, bv, fq, fk, vT);
    attn_kernel<<<dim3(Nn / 32, Bn, 8), 256, 0, stream>>>(fq, fk, vT, topo, pacc, pl);
    oproj_kernel<<<(Bn * Nn) / 8, 256, 0, stream>>>(pacc, pl, Wo, bo, out);
}

// Round 6
// 348.785 us; speedup vs baseline: 1.1375x; 1.1375x over previous
//
#include <hip/hip_runtime.h>
#include <math.h>

#define Bn 4
#define Nn 2048
#define Hn 8
#define HDn 32
#define Dn 256
#define MHALF 1024  // m-split: 2 partials merged in oproj

typedef _Float16 h1;
typedef __attribute__((ext_vector_type(8))) _Float16 h8;
typedef __attribute__((ext_vector_type(4))) float fx4;

#define QSCALE 0.35355339059327373f  // 2/sqrt(HD): applied at exp time
// |S_raw| <= HD = 32, |S_raw*QSCALE*topo| <= 11.32 -> fixed softmax shift safe:
// p = e^{S-4} in [2.2e-7, 1503] -- fits f16, no running max needed.
#define SOFTMAX_SHIFT 4.0f

// ---------------------------------------------------------------------------
// Kernel 0: W -> f16 transpose via LDS tiles (coalesced both sides)
//   WT[w][out][d], 64x64 tiles
// ---------------------------------------------------------------------------
__global__ __launch_bounds__(256) void cvtW_kernel(
    const float* __restrict__ Wq, const float* __restrict__ Wk,
    const float* __restrict__ Wv, h1* __restrict__ WT)
{
    __shared__ float tw[64][65];
    const int w = blockIdx.z;
    const int d0 = blockIdx.y * 64, o0 = blockIdx.x * 64;
    const float* W = (w == 0) ? Wq : (w == 1) ? Wk : Wv;
    const int rr = threadIdx.x >> 6, cc = threadIdx.x & 63;
#pragma unroll
    for (int i = 0; i < 16; ++i)
        tw[rr + i * 4][cc] = W[(size_t)(d0 + rr + i * 4) * 256 + o0 + cc];
    __syncthreads();
#pragma unroll
    for (int i = 0; i < 16; ++i) {
        const int row = rr + i * 4;
        WT[(size_t)w * 65536 + (size_t)(o0 + row) * 256 + d0 + cc] = (h1)tw[cc][row];
    }
}

// ---------------------------------------------------------------------------
// Kernel 1: QKV projection via f16 MFMA (x split hi/lo for ~f32 accuracy).
// grid.y = wsel*2 + hg : one of 3 weights x one 128-col half.
// Block = 4 waves x 16 rows = 64 rows x 128 cols. Per-kstep x conversion
// keeps VGPR ~95 (acc 8x4=32) -> 4 waves/SIMD (amdgpu_waves_per_eu pins it).
// Epilogue q/k: features -> LDS -> coalesced h8 stores. v -> LDS transpose.
// Fragment layouts (verified gfx950):
//   A: A[m=lane&15][k=quad*8+j], B: B[k=quad*8+j][n=lane&15],
//   C/D: row=quad*4+reg, col=lane&15
// ---------------------------------------------------------------------------
__global__ __launch_bounds__(256) __attribute__((amdgpu_waves_per_eu(4, 4)))
void proj_kernel(
    const float* __restrict__ x, const h1* __restrict__ WT,
    const float* __restrict__ bq, const float* __restrict__ bk,
    const float* __restrict__ bv,
    h1* __restrict__ fq, h1* __restrict__ fk, h1* __restrict__ vT)
{
    __shared__ __align__(16) h1 fbuf[64][264];  // 33.8 KB (v path uses a slice)
    const int tid = threadIdx.x;
    const int w = tid >> 6;
    const int lane = tid & 63;
    const int quad = lane >> 4;
    const int l15 = lane & 15;
    const int wsel = blockIdx.y >> 1;
    const int hg = blockIdx.y & 1;       // column half: cols hg*128..hg*128+127
    const int r0 = blockIdx.x * 64;
    const int arow = r0 + w * 16 + l15;
    const int b = r0 >> 11, n0 = r0 & (Nn - 1);

    const h1* WTw = WT + (size_t)wsel * 65536;
    fx4 acc[8];
#pragma unroll
    for (int ct = 0; ct < 8; ++ct) acc[ct] = (fx4){0.f, 0.f, 0.f, 0.f};

    for (int ks = 0; ks < 8; ++ks) {
        // x slice -> hi/lo f16 (transient)
        float xv[8];
        *(float4*)&xv[0] = *(const float4*)&x[(size_t)arow * 256 + ks * 32 + quad * 8];
        *(float4*)&xv[4] = *(const float4*)&x[(size_t)arow * 256 + ks * 32 + quad * 8 + 4];
        h8 Ahi, Alo;
#pragma unroll
        for (int j = 0; j < 8; ++j) {
            const h1 hi = (h1)xv[j];
            Ahi[j] = hi;
            Alo[j] = (h1)(xv[j] - (float)hi);
        }
        h8 Bf[8];
#pragma unroll
        for (int ct = 0; ct < 8; ++ct)
            Bf[ct] = *(const h8*)&WTw[(size_t)(hg * 128 + ct * 16 + l15) * 256 + ks * 32 + quad * 8];
#pragma unroll
        for (int ct = 0; ct < 8; ++ct) {
            acc[ct] = __builtin_amdgcn_mfma_f32_16x16x32_f16(Ahi, Bf[ct], acc[ct], 0, 0, 0);
            acc[ct] = __builtin_amdgcn_mfma_f32_16x16x32_f16(Alo, Bf[ct], acc[ct], 0, 0, 0);
        }
    }

    const float* bias = (wsel == 0) ? bq : (wsel == 1) ? bk : bv;

    if (wsel < 2) {
        h1* f = (wsel == 0) ? fq : fk;
        // stage features: fbuf[lrow][hh4*64 + dd (+32)]
#pragma unroll
        for (int ct = 0; ct < 8; ++ct) {
            const int c = ct * 16 + l15;          // local col 0..127
            const float bb = bias[hg * 128 + c];
            const int hh4 = c >> 5, dd = c & 31;
#pragma unroll
            for (int r = 0; r < 4; ++r) {
                float sv, cv;
                __sincosf(acc[ct][r] + bb, &sv, &cv);
                h1* fp = &fbuf[w * 16 + quad * 4 + r][hh4 * 64 + dd];
                fp[0]  = (h1)cv;
                fp[32] = (h1)sv;
            }
        }
        __syncthreads();
        // coalesced store: 2048 h8-chunks / 256 threads = 8 each
        const int row = tid >> 2, q4 = tid & 3;
#pragma unroll
        for (int g = 0; g < 8; ++g) {
            const int chunk = q4 + g * 4;         // 0..31
            const int hh4 = chunk >> 3, within = chunk & 7;
            const h8 val = *(const h8*)&fbuf[row][hh4 * 64 + within * 8];
            const int head = hg * 4 + hh4;
            *(h8*)&f[((size_t)(b * Hn + head) * Nn + n0 + row) * 64 + within * 8] = val;
        }
    } else {
        // v: stage to LDS, transposed write -> vT (cols hg*128 -> heads hg*4..+3)
        h1 (*vst)[132] = (h1(*)[132])fbuf;
#pragma unroll
        for (int ct = 0; ct < 8; ++ct) {
            const int c = ct * 16 + l15;
            const float bb = bias[hg * 128 + c];
#pragma unroll
            for (int r = 0; r < 4; ++r)
                vst[w * 16 + quad * 4 + r][c] = (h1)(acc[ct][r] + bb);
        }
        __syncthreads();
        const int c2 = tid & 127, half = tid >> 7;
        const int head = hg * 4 + (c2 >> 5), dd = c2 & 31;
        h1* vp = vT + ((size_t)((b * Hn + head) * HDn + dd)) * Nn + n0;
#pragma unroll
        for (int g = 0; g < 4; ++g) {
            const int gg = half * 4 + g;
            h8 pk;
#pragma unroll
            for (int j = 0; j < 8; ++j) pk[j] = vst[gg * 8 + j][c2];
            *(h8*)(vp + gg * 8) = pk;
        }
    }
}

// ---------------------------------------------------------------------------
// Kernel 2: fused attention, barrier-free, topo-double-buffered.
// Block = 512 thr = 8 waves = 4 heads x 2 q-subtiles (64 q-rows/block ->
// halved kf/vT L2 amplification). Grid 32x4x4 = 512 blocks = 4096 waves =
// exactly 4 waves/SIMD in one shot. amdgpu_waves_per_eu(4,4) pins the
// register budget at 128 so the topo prefetch (unroll-2, two named buffers,
// NO rotation copies) does not spill (r3/r5 failure mode).
// Fixed-shift softmax: no reductions in the loop.
// ---------------------------------------------------------------------------
__global__ __launch_bounds__(512) __attribute__((amdgpu_waves_per_eu(4, 4)))
void attn_kernel(
    const h1* __restrict__ fq, const h1* __restrict__ fk, const h1* __restrict__ vT,
    const float* __restrict__ topo, float* __restrict__ pacc, float* __restrict__ pl)
{
    __shared__ __align__(16) h1 Pw[8][32][40];  // per-wave P transpose buffer

    const int b = blockIdx.y;
    const int z = blockIdx.z;          // z = hg + 2*mh
    const int mh = z >> 1;
    const int tid = threadIdx.x;
    const int w = tid >> 6;
    const int h = (z & 1) * 4 + (w & 3);
    const int n0 = blockIdx.x * 64 + (w >> 2) * 32;  // this wave's 32 q-rows
    const int lane = tid & 63;
    const int quad = lane >> 4;
    const int l15 = lane & 15;

    const h1* qfh = fq + (size_t)(b * Hn + h) * Nn * 64;
    const h1* kfh = fk + (size_t)(b * Hn + h) * Nn * 64;
    const h1* vTh = vT + (size_t)(b * Hn + h) * HDn * Nn;
    const float* tpb = topo + (size_t)b * Nn * Nn + (size_t)n0 * Nn;

    h8 qfr[2][2];
#pragma unroll
    for (int qs = 0; qs < 2; ++qs)
#pragma unroll
        for (int ks = 0; ks < 2; ++ks)
            qfr[qs][ks] = *(const h8*)(qfh + (size_t)(n0 + qs * 16 + l15) * 64 + ks * 32 + quad * 8);

    fx4 acc[2][2];
    float lsum[2][4];
#pragma unroll
    for (int qs = 0; qs < 2; ++qs) {
#pragma unroll
        for (int ds = 0; ds < 2; ++ds) acc[qs][ds] = (fx4){0.f, 0.f, 0.f, 0.f};
#pragma unroll
        for (int r = 0; r < 4; ++r) lsum[qs][r] = 0.f;
    }

    const int mbase = mh * MHALF;
    const fx4 z4 = {0.f, 0.f, 0.f, 0.f};

#define LOADTP(TP, M0)                                                         \
    do {                                                                       \
        _Pragma("unroll") for (int qs = 0; qs < 2; ++qs)                       \
            _Pragma("unroll") for (int r = 0; r < 4; ++r) {                    \
                const float* tr = tpb +                                        \
                    (size_t)(qs * 16 + quad * 4 + r) * Nn + (M0) + l15;        \
                TP[qs][r][0] = tr[0];                                          \
                TP[qs][r][1] = tr[16];                                         \
            }                                                                  \
    } while (0)

#define COMPUTE_TILE(M0, TP)                                                   \
    do {                                                                       \
        h8 kfr[2][2];                                                          \
        _Pragma("unroll") for (int ms = 0; ms < 2; ++ms)                       \
            _Pragma("unroll") for (int ks = 0; ks < 2; ++ks)                   \
                kfr[ms][ks] = *(const h8*)(kfh +                               \
                    (size_t)((M0) + ms * 16 + l15) * 64 + ks * 32 + quad * 8); \
        fx4 S[2][2];                                                           \
        _Pragma("unroll") for (int qs = 0; qs < 2; ++qs)                       \
            _Pragma("unroll") for (int ms = 0; ms < 2; ++ms) {                 \
                fx4 tmp = __builtin_amdgcn_mfma_f32_16x16x32_f16(              \
                    qfr[qs][0], kfr[ms][0], z4, 0, 0, 0);                      \
                S[qs][ms] = __builtin_amdgcn_mfma_f32_16x16x32_f16(            \
                    qfr[qs][1], kfr[ms][1], tmp, 0, 0, 0);                     \
            }                                                                  \
        h8 bV[2];                                                              \
        _Pragma("unroll") for (int ds = 0; ds < 2; ++ds)                       \
            bV[ds] = *(const h8*)(vTh +                                        \
                (size_t)(ds * 16 + l15) * Nn + (M0) + quad * 8);               \
        _Pragma("unroll") for (int qs = 0; qs < 2; ++qs)                       \
            _Pragma("unroll") for (int ms = 0; ms < 2; ++ms)                   \
                _Pragma("unroll") for (int r = 0; r < 4; ++r) {                \
                    const float ts = S[qs][ms][r] * TP[qs][r][ms];             \
                    const float p = __expf(fmaf(ts, QSCALE, -SOFTMAX_SHIFT));  \
                    lsum[qs][r] += p;                                          \
                    Pw[w][qs * 16 + quad * 4 + r][ms * 16 + l15] = (h1)p;      \
                }                                                              \
        h8 aP[2];                                                              \
        _Pragma("unroll") for (int qs = 0; qs < 2; ++qs)                       \
            aP[qs] = *(const h8*)&Pw[w][qs * 16 + l15][quad * 8];              \
        _Pragma("unroll") for (int qs = 0; qs < 2; ++qs)                       \
            _Pragma("unroll") for (int ds = 0; ds < 2; ++ds)                   \
                acc[qs][ds] = __builtin_amdgcn_mfma_f32_16x16x32_f16(          \
                    aP[qs], bV[ds], acc[qs][ds], 0, 0, 0);                     \
    } while (0)

    float tpA[2][4][2], tpB[2][4][2];
    LOADTP(tpA, mbase);

    for (int ot = 0; ot < MHALF / 64; ++ot) {   // 16 outer = 32 m-tiles
        const int m0 = mbase + ot * 64;
        LOADTP(tpB, m0 + 32);                   // prefetch tile 2ot+1
        COMPUTE_TILE(m0, tpA);
        const int mA = (ot < MHALF / 64 - 1) ? m0 + 64 : m0;  // clamp
        LOADTP(tpA, mA);                        // prefetch tile 2ot+2
        COMPUTE_TILE(m0 + 32, tpB);
    }
#undef LOADTP
#undef COMPUTE_TILE

    // epilogue: reduce l across the 16 col-lanes, write partials
#pragma unroll
    for (int qs = 0; qs < 2; ++qs)
#pragma unroll
        for (int r = 0; r < 4; ++r)
#pragma unroll
            for (int off = 1; off <= 8; off <<= 1)
                lsum[qs][r] += __shfl_xor(lsum[qs][r], off);

    float* paccm = pacc + (size_t)mh * Bn * Nn * Dn;
    float* plm   = pl   + (size_t)mh * Bn * Nn * Hn;
#pragma unroll
    for (int qs = 0; qs < 2; ++qs)
#pragma unroll
        for (int r = 0; r < 4; ++r) {
            const size_t grow = (size_t)b * Nn + n0 + qs * 16 + quad * 4 + r;
            paccm[grow * Dn + h * HDn + l15]      = acc[qs][0][r];
            paccm[grow * Dn + h * HDn + 16 + l15] = acc[qs][1][r];
            if (l15 == 0) plm[grow * Hn + h] = lsum[qs][r];
        }
}

// ---------------------------------------------------------------------------
// Kernel 3: merge 2 partials + output projection. 8 rows/block, thread=col.
// ---------------------------------------------------------------------------
__global__ __launch_bounds__(256) void oproj_kernel(
    const float* __restrict__ pacc, const float* __restrict__ pl,
    const float* __restrict__ Wo, const float* __restrict__ bo,
    float* __restrict__ out)
{
    __shared__ float ysT[256][12];  // [col][row], float4-aligned rows
    const int t = threadIdx.x;
    const int r0 = blockIdx.x * 8;
    const int h = t >> 5;
    const size_t PACC = (size_t)Bn * Nn * Dn;
    const size_t PL = (size_t)Bn * Nn * Hn;
#pragma unroll
    for (int i = 0; i < 8; ++i) {
        const size_t row = (size_t)(r0 + i);
        float l = 0.f, yv = 0.f;
#pragma unroll
        for (int m = 0; m < 2; ++m) {
            l  += pl[m * PL + row * Hn + h];
            yv += pacc[m * PACC + row * Dn + t];
        }
        ysT[t][i] = yv * __builtin_amdgcn_rcpf(l);
    }
    __syncthreads();

    float acc8[8];
#pragma unroll
    for (int i = 0; i < 8; ++i) acc8[i] = 0.f;
#pragma unroll 4
    for (int d = 0; d < 256; ++d) {
        const float wv = Wo[d * 256 + t];
        float yy[8];
        *(float4*)&yy[0] = *(const float4*)&ysT[d][0];  // broadcast reads
        *(float4*)&yy[4] = *(const float4*)&ysT[d][4];
#pragma unroll
        for (int i = 0; i < 8; ++i) acc8[i] = fmaf(yy[i], wv, acc8[i]);
    }
    const float bb = bo[t];
#pragma unroll
    for (int i = 0; i < 8; ++i)
        out[(size_t)(r0 + i) * 256 + t] = acc8[i] + bb;
}

// ---------------------------------------------------------------------------
extern "C" void kernel_launch(void* const* d_in, const int* in_sizes, int n_in,
                              void* d_out, int out_size, void* d_ws, size_t ws_size,
                              hipStream_t stream)
{
    const float* x    = (const float*)d_in[0];
    const float* topo = (const float*)d_in[1];
    const float* Wq   = (const float*)d_in[2];
    const float* bq   = (const float*)d_in[3];
    const float* Wk   = (const float*)d_in[4];
    const float* bk   = (const float*)d_in[5];
    const float* Wv   = (const float*)d_in[6];
    const float* bv   = (const float*)d_in[7];
    const float* Wo   = (const float*)d_in[8];
    const float* bo   = (const float*)d_in[9];
    float* out = (float*)d_out;

    char* ws = (char*)d_ws;
    const size_t MB = 1024 * 1024;
    // ws: WT 384KB @0 | fq 8MB @1 | fk 8MB @9 | vT 4MB @17 | pacc 16MB @21 | pl 0.5MB @37
    h1* WT = (h1*)ws;
    h1* fq = (h1*)(ws + 1 * MB);
    h1* fk = (h1*)(ws + 9 * MB);
    h1* vT = (h1*)(ws + 17 * MB);
    float* pacc = (float*)(ws + 21 * MB);
    float* pl   = (float*)(ws + 37 * MB);

    cvtW_kernel<<<dim3(4, 4, 3), 256, 0, stream>>>(Wq, Wk, Wv, WT);
    proj_kernel<<<dim3(128, 6), 256, 0, stream>>>(x, WT, bq, bk, bv, fq, fk, vT);
    attn_kernel<<<dim3(32, Bn, 4), 512, 0, stream>>>(fq, fk, vT, topo, pacc, pl);
    oproj_kernel<<<(Bn * Nn) / 8, 256, 0, stream>>>(pacc, pl, Wo, bo, out);
}

// Round 7
// 267.359 us; speedup vs baseline: 1.4839x; 1.3046x over previous
//
#include <hip/hip_runtime.h>
#include <math.h>

#define Bn 4
#define Nn 2048
#define Hn 8
#define HDn 32
#define Dn 256
#define MHALF 1024  // m-split: 2 partials merged in oproj

typedef _Float16 h1;
typedef __attribute__((ext_vector_type(8))) _Float16 h8;
typedef __attribute__((ext_vector_type(4))) float fx4;

#define QSCALE 0.35355339059327373f
// |S_raw| <= HD = 32, |S_raw*QSCALE*topo| <= 11.32 -> fixed softmax shift safe:
// p = e^{S-4} in [2.2e-7, 1503] -- fits f16, no running max needed.
#define SOFTMAX_SHIFT 4.0f

// ---------------------------------------------------------------------------
// Kernel 0: W -> f16 transpose via LDS tiles (coalesced both sides)
// ---------------------------------------------------------------------------
__global__ __launch_bounds__(256) void cvtW_kernel(
    const float* __restrict__ Wq, const float* __restrict__ Wk,
    const float* __restrict__ Wv, h1* __restrict__ WT)
{
    __shared__ float tw[64][65];
    const int w = blockIdx.z;
    const int d0 = blockIdx.y * 64, o0 = blockIdx.x * 64;
    const float* W = (w == 0) ? Wq : (w == 1) ? Wk : Wv;
    const int rr = threadIdx.x >> 6, cc = threadIdx.x & 63;
#pragma unroll
    for (int i = 0; i < 16; ++i)
        tw[rr + i * 4][cc] = W[(size_t)(d0 + rr + i * 4) * 256 + o0 + cc];
    __syncthreads();
#pragma unroll
    for (int i = 0; i < 16; ++i) {
        const int row = rr + i * 4;
        WT[(size_t)w * 65536 + (size_t)(o0 + row) * 256 + d0 + cc] = (h1)tw[cc][row];
    }
}

// ---------------------------------------------------------------------------
// Kernel 1: QKV projection via f16 MFMA (x split hi/lo for ~f32 accuracy).
// Same structure as r6; ONLY change: __sincosf -> __sinf/__cosf (hw
// v_sin/v_cos, ~10 cyc vs ~60+ for precise ocml sincos; error ~2e-5 is far
// below f16 storage quantization).
// ---------------------------------------------------------------------------
__global__ __launch_bounds__(256) __attribute__((amdgpu_waves_per_eu(4, 4)))
void proj_kernel(
    const float* __restrict__ x, const h1* __restrict__ WT,
    const float* __restrict__ bq, const float* __restrict__ bk,
    const float* __restrict__ bv,
    h1* __restrict__ fq, h1* __restrict__ fk, h1* __restrict__ vT)
{
    __shared__ __align__(16) h1 fbuf[64][264];
    const int tid = threadIdx.x;
    const int w = tid >> 6;
    const int lane = tid & 63;
    const int quad = lane >> 4;
    const int l15 = lane & 15;
    const int wsel = blockIdx.y >> 1;
    const int hg = blockIdx.y & 1;
    const int r0 = blockIdx.x * 64;
    const int arow = r0 + w * 16 + l15;
    const int b = r0 >> 11, n0 = r0 & (Nn - 1);

    const h1* WTw = WT + (size_t)wsel * 65536;
    fx4 acc[8];
#pragma unroll
    for (int ct = 0; ct < 8; ++ct) acc[ct] = (fx4){0.f, 0.f, 0.f, 0.f};

    for (int ks = 0; ks < 8; ++ks) {
        float xv[8];
        *(float4*)&xv[0] = *(const float4*)&x[(size_t)arow * 256 + ks * 32 + quad * 8];
        *(float4*)&xv[4] = *(const float4*)&x[(size_t)arow * 256 + ks * 32 + quad * 8 + 4];
        h8 Ahi, Alo;
#pragma unroll
        for (int j = 0; j < 8; ++j) {
            const h1 hi = (h1)xv[j];
            Ahi[j] = hi;
            Alo[j] = (h1)(xv[j] - (float)hi);
        }
        h8 Bf[8];
#pragma unroll
        for (int ct = 0; ct < 8; ++ct)
            Bf[ct] = *(const h8*)&WTw[(size_t)(hg * 128 + ct * 16 + l15) * 256 + ks * 32 + quad * 8];
#pragma unroll
        for (int ct = 0; ct < 8; ++ct) {
            acc[ct] = __builtin_amdgcn_mfma_f32_16x16x32_f16(Ahi, Bf[ct], acc[ct], 0, 0, 0);
            acc[ct] = __builtin_amdgcn_mfma_f32_16x16x32_f16(Alo, Bf[ct], acc[ct], 0, 0, 0);
        }
    }

    const float* bias = (wsel == 0) ? bq : (wsel == 1) ? bk : bv;

    if (wsel < 2) {
        h1* f = (wsel == 0) ? fq : fk;
#pragma unroll
        for (int ct = 0; ct < 8; ++ct) {
            const int c = ct * 16 + l15;
            const float bb = bias[hg * 128 + c];
            const int hh4 = c >> 5, dd = c & 31;
#pragma unroll
            for (int r = 0; r < 4; ++r) {
                const float val = acc[ct][r] + bb;
                const float sv = __sinf(val), cv = __cosf(val);
                h1* fp = &fbuf[w * 16 + quad * 4 + r][hh4 * 64 + dd];
                fp[0]  = (h1)cv;
                fp[32] = (h1)sv;
            }
        }
        __syncthreads();
        const int row = tid >> 2, q4 = tid & 3;
#pragma unroll
        for (int g = 0; g < 8; ++g) {
            const int chunk = q4 + g * 4;
            const int hh4 = chunk >> 3, within = chunk & 7;
            const h8 val = *(const h8*)&fbuf[row][hh4 * 64 + within * 8];
            const int head = hg * 4 + hh4;
            *(h8*)&f[((size_t)(b * Hn + head) * Nn + n0 + row) * 64 + within * 8] = val;
        }
    } else {
        h1 (*vst)[132] = (h1(*)[132])fbuf;
#pragma unroll
        for (int ct = 0; ct < 8; ++ct) {
            const int c = ct * 16 + l15;
            const float bb = bias[hg * 128 + c];
#pragma unroll
            for (int r = 0; r < 4; ++r)
                vst[w * 16 + quad * 4 + r][c] = (h1)(acc[ct][r] + bb);
        }
        __syncthreads();
        const int c2 = tid & 127, half = tid >> 7;
        const int head = hg * 4 + (c2 >> 5), dd = c2 & 31;
        h1* vp = vT + ((size_t)((b * Hn + head) * HDn + dd)) * Nn + n0;
#pragma unroll
        for (int g = 0; g < 4; ++g) {
            const int gg = half * 4 + g;
            h8 pk;
#pragma unroll
            for (int j = 0; j < 8; ++j) pk[j] = vst[gg * 8 + j][c2];
            *(h8*)(vp + gg * 8) = pk;
        }
    }
}

// ---------------------------------------------------------------------------
// Kernel 2: fused attention. Block = 512 thr = 8 waves = ALL 8 heads of one
// (b, 32 q-rows, m-half) -> topo tile shared block-wide (67 MB HBM minimum).
// Topo pipelined through an LDS double buffer: each thread keeps a float2
// prefetch register (fits the 64-arch-VGPR budget; the r3/r5/r6 register
// pipelines all spilled), writes it to LDS, issues the next tile's load,
// then a RAW s_barrier (inline asm, lgkmcnt(0) only) -- avoids the
// compiler's vmcnt(0) drain at __syncthreads so the global prefetch stays
// in flight across the whole compute phase. One barrier/iter + 2 buffers
// is race-free (barrier k guarantees all reads of buffer b at iter k-1
// are done before iter k+1 overwrites it).
// Fixed-shift softmax: no reductions in the loop.
// ---------------------------------------------------------------------------
__global__ __launch_bounds__(512, 4) void attn_kernel(
    const h1* __restrict__ fq, const h1* __restrict__ fk, const h1* __restrict__ vT,
    const float* __restrict__ topo, float* __restrict__ pacc, float* __restrict__ pl)
{
    __shared__ __align__(16) h1 Pw[8][32][40];   // 20 KB per-wave P buffers
    __shared__ float tbuf[2][32][33];            // 8.4 KB topo double buffer

    const int b = blockIdx.y;
    const int mh = blockIdx.z;
    const int n0 = blockIdx.x * 32;
    const int tid = threadIdx.x;
    const int w = tid >> 6;        // wave id = head
    const int h = w;
    const int lane = tid & 63;
    const int quad = lane >> 4;
    const int l15 = lane & 15;

    const h1* qfh = fq + (size_t)(b * Hn + h) * Nn * 64;
    const h1* kfh = fk + (size_t)(b * Hn + h) * Nn * 64;
    const h1* vTh = vT + (size_t)(b * Hn + h) * HDn * Nn;

    // topo cooperative-load mapping: thread -> (row, 2 cols)
    const int trow = tid >> 4, tcol = (tid & 15) * 2;
    const float* tpg = topo + (size_t)b * Nn * Nn + (size_t)(n0 + trow) * Nn + tcol;

    h8 qfr[2][2];
#pragma unroll
    for (int qs = 0; qs < 2; ++qs)
#pragma unroll
        for (int ks = 0; ks < 2; ++ks)
            qfr[qs][ks] = *(const h8*)(qfh + (size_t)(n0 + qs * 16 + l15) * 64 + ks * 32 + quad * 8);

    fx4 acc[2][2];
    float lsum[2][4];
#pragma unroll
    for (int qs = 0; qs < 2; ++qs) {
#pragma unroll
        for (int ds = 0; ds < 2; ++ds) acc[qs][ds] = (fx4){0.f, 0.f, 0.f, 0.f};
#pragma unroll
        for (int r = 0; r < 4; ++r) lsum[qs][r] = 0.f;
    }

    const int mbase = mh * MHALF;
    const fx4 z4 = {0.f, 0.f, 0.f, 0.f};

    float2 rt = *(const float2*)(tpg + mbase);   // prefetch tile 0

    for (int it = 0; it < MHALF / 32; ++it) {
        const int m0 = mbase + it * 32;
        const int cur = it & 1;

        // commit prefetched topo tile to LDS, issue next tile's load
        tbuf[cur][trow][tcol]     = rt.x;
        tbuf[cur][trow][tcol + 1] = rt.y;
        if (it < MHALF / 32 - 1) rt = *(const float2*)(tpg + m0 + 32);
        // raw barrier: waits own LDS writes only; global prefetch stays in flight
        __asm__ volatile("s_waitcnt lgkmcnt(0)\n\ts_barrier" ::: "memory");

        // K fragments + V fragments (per-head, L2-served)
        h8 kfr[2][2];
#pragma unroll
        for (int ms = 0; ms < 2; ++ms)
#pragma unroll
            for (int ks = 0; ks < 2; ++ks)
                kfr[ms][ks] = *(const h8*)(kfh + (size_t)(m0 + ms * 16 + l15) * 64 + ks * 32 + quad * 8);
        h8 bV[2];
#pragma unroll
        for (int ds = 0; ds < 2; ++ds)
            bV[ds] = *(const h8*)(vTh + (size_t)(ds * 16 + l15) * Nn + m0 + quad * 8);

        // S = Qf @ Kf^T
        fx4 S[2][2];
#pragma unroll
        for (int qs = 0; qs < 2; ++qs)
#pragma unroll
            for (int ms = 0; ms < 2; ++ms) {
                fx4 tmp = __builtin_amdgcn_mfma_f32_16x16x32_f16(qfr[qs][0], kfr[ms][0], z4, 0, 0, 0);
                S[qs][ms] = __builtin_amdgcn_mfma_f32_16x16x32_f16(qfr[qs][1], kfr[ms][1], tmp, 0, 0, 0);
            }

        // p = e^{S*topo*QSCALE - 4}; topo from LDS (2-way-free banks via pad 33)
#pragma unroll
        for (int qs = 0; qs < 2; ++qs)
#pragma unroll
            for (int ms = 0; ms < 2; ++ms)
#pragma unroll
                for (int r = 0; r < 4; ++r) {
                    const float tv = tbuf[cur][qs * 16 + quad * 4 + r][ms * 16 + l15];
                    const float p = __expf(fmaf(S[qs][ms][r] * tv, QSCALE, -SOFTMAX_SHIFT));
                    lsum[qs][r] += p;
                    Pw[w][qs * 16 + quad * 4 + r][ms * 16 + l15] = (h1)p;
                }
        __asm__ volatile("s_waitcnt lgkmcnt(0)" ::: "memory");

        // PV
        h8 aP[2];
#pragma unroll
        for (int qs = 0; qs < 2; ++qs)
            aP[qs] = *(const h8*)&Pw[w][qs * 16 + l15][quad * 8];
#pragma unroll
        for (int qs = 0; qs < 2; ++qs)
#pragma unroll
            for (int ds = 0; ds < 2; ++ds)
                acc[qs][ds] = __builtin_amdgcn_mfma_f32_16x16x32_f16(aP[qs], bV[ds], acc[qs][ds], 0, 0, 0);
    }

    // epilogue: reduce l across the 16 col-lanes, write partials
#pragma unroll
    for (int qs = 0; qs < 2; ++qs)
#pragma unroll
        for (int r = 0; r < 4; ++r)
#pragma unroll
            for (int off = 1; off <= 8; off <<= 1)
                lsum[qs][r] += __shfl_xor(lsum[qs][r], off);

    float* paccm = pacc + (size_t)mh * Bn * Nn * Dn;
    float* plm   = pl   + (size_t)mh * Bn * Nn * Hn;
#pragma unroll
    for (int qs = 0; qs < 2; ++qs)
#pragma unroll
        for (int r = 0; r < 4; ++r) {
            const size_t grow = (size_t)b * Nn + n0 + qs * 16 + quad * 4 + r;
            paccm[grow * Dn + h * HDn + l15]      = acc[qs][0][r];
            paccm[grow * Dn + h * HDn + 16 + l15] = acc[qs][1][r];
            if (l15 == 0) plm[grow * Hn + h] = lsum[qs][r];
        }
}

// ---------------------------------------------------------------------------
// Kernel 3: merge 2 partials + output projection. 8 rows/block, thread=col.
// ---------------------------------------------------------------------------
__global__ __launch_bounds__(256) void oproj_kernel(
    const float* __restrict__ pacc, const float* __restrict__ pl,
    const float* __restrict__ Wo, const float* __restrict__ bo,
    float* __restrict__ out)
{
    __shared__ float ysT[256][12];
    const int t = threadIdx.x;
    const int r0 = blockIdx.x * 8;
    const int h = t >> 5;
    const size_t PACC = (size_t)Bn * Nn * Dn;
    const size_t PL = (size_t)Bn * Nn * Hn;
#pragma unroll
    for (int i = 0; i < 8; ++i) {
        const size_t row = (size_t)(r0 + i);
        float l = 0.f, yv = 0.f;
#pragma unroll
        for (int m = 0; m < 2; ++m) {
            l  += pl[m * PL + row * Hn + h];
            yv += pacc[m * PACC + row * Dn + t];
        }
        ysT[t][i] = yv * __builtin_amdgcn_rcpf(l);
    }
    __syncthreads();

    float acc8[8];
#pragma unroll
    for (int i = 0; i < 8; ++i) acc8[i] = 0.f;
#pragma unroll 4
    for (int d = 0; d < 256; ++d) {
        const float wv = Wo[d * 256 + t];
        float yy[8];
        *(float4*)&yy[0] = *(const float4*)&ysT[d][0];
        *(float4*)&yy[4] = *(const float4*)&ysT[d][4];
#pragma unroll
        for (int i = 0; i < 8; ++i) acc8[i] = fmaf(yy[i], wv, acc8[i]);
    }
    const float bb = bo[t];
#pragma unroll
    for (int i = 0; i < 8; ++i)
        out[(size_t)(r0 + i) * 256 + t] = acc8[i] + bb;
}

// ---------------------------------------------------------------------------
extern "C" void kernel_launch(void* const* d_in, const int* in_sizes, int n_in,
                              void* d_out, int out_size, void* d_ws, size_t ws_size,
                              hipStream_t stream)
{
    const float* x    = (const float*)d_in[0];
    const float* topo = (const float*)d_in[1];
    const float* Wq   = (const float*)d_in[2];
    const float* bq   = (const float*)d_in[3];
    const float* Wk   = (const float*)d_in[4];
    const float* bk   = (const float*)d_in[5];
    const float* Wv   = (const float*)d_in[6];
    const float* bv   = (const float*)d_in[7];
    const float* Wo   = (const float*)d_in[8];
    const float* bo   = (const float*)d_in[9];
    float* out = (float*)d_out;

    char* ws = (char*)d_ws;
    const size_t MB = 1024 * 1024;
    h1* WT = (h1*)ws;
    h1* fq = (h1*)(ws + 1 * MB);
    h1* fk = (h1*)(ws + 9 * MB);
    h1* vT = (h1*)(ws + 17 * MB);
    float* pacc = (float*)(ws + 21 * MB);
    float* pl   = (float*)(ws + 37 * MB);

    cvtW_kernel<<<dim3(4, 4, 3), 256, 0, stream>>>(Wq, Wk, Wv, WT);
    proj_kernel<<<dim3(128, 6), 256, 0, stream>>>(x, WT, bq, bk, bv, fq, fk, vT);
    attn_kernel<<<dim3(Nn / 32, Bn, 2), 512, 0, stream>>>(fq, fk, vT, topo, pacc, pl);
    oproj_kernel<<<(Bn * Nn) / 8, 256, 0, stream>>>(pacc, pl, Wo, bo, out);
}